// Round 9
// baseline (137.593 us; speedup 1.0000x reference)
//
#include <hip/hip_runtime.h>

#define NN 50000
#define NNP 50176   // Ab rows padded to multiple of 256 (gemm block = 256 nodes)
#define NE 640000
#define IC 128
#define HC 256
#define OC 3

#define TOBF16_BLOCKS (NN * IC / 4 / 256)          // 6250
#define WPACK_BLOCKS  32
#define ZERO_BLOCKS   ((NN + 1 + 255) / 256)       // 196 (degi[0..NN-1] + counter at degi[NN])
#define GR0_BLOCKS    293                          // zero g+r: 1,200,128 B = 75,008 float4 / 256

typedef __attribute__((ext_vector_type(8))) short short8;
typedef __attribute__((ext_vector_type(4))) float f32x4;

__device__ __forceinline__ unsigned short f2bf(float f) {   // fp32 -> bf16 RNE
    unsigned int u = __float_as_uint(f);
    unsigned int r = u + 0x7FFFu + ((u >> 16) & 1u);
    return (unsigned short)(r >> 16);
}
__device__ __forceinline__ float bflo(unsigned int v) { return __uint_as_float(v << 16); }
__device__ __forceinline__ float bfhi(unsigned int v) { return __uint_as_float(v & 0xffff0000u); }

// ---------------- prep: zero degi+counter+g+r | x->bf16 | pack W ----------------
__global__ __launch_bounds__(256) void k_prep(const float* __restrict__ x,
                                              const float* __restrict__ Wl0,
                                              const float* __restrict__ Wr0,
                                              unsigned short* __restrict__ Ab,
                                              unsigned short* __restrict__ Bp,
                                              int* __restrict__ degi,
                                              float4* __restrict__ gr) {
    int b = blockIdx.x;
    int t = threadIdx.x;
    if (b < TOBF16_BLOCKS) {
        // x -> bf16 into right half of Ab (Ab: ushort[NNP][256], cols 128..255 = x)
        int i = b * 256 + t;                  // over NN*IC/4 float4s
        int n = i >> 5;
        int c = (i & 31) * 4;
        float4 v = ((const float4*)x)[i];
        ushort4 o;
        o.x = f2bf(v.x); o.y = f2bf(v.y); o.z = f2bf(v.z); o.w = f2bf(v.w);
        *(ushort4*)&Ab[(size_t)n * 256 + 128 + c] = o;
    } else if (b < TOBF16_BLOCKS + WPACK_BLOCKS) {
        // pack [Wl0;Wr0] into MFMA B-fragment order:
        // Bp[kt(8)][nt(16)][lane(64)][e(8)], B[k][n]: k=kt*32+(lane>>4)*8+e, n=nt*16+(lane&15)
        int tt = (b - TOBF16_BLOCKS) * 256 + t;     // 8192 threads
        int l = tt & 63;
        int nt = (tt >> 6) & 15;
        int kt = tt >> 10;
        int n = nt * 16 + (l & 15);
        int kbase = kt * 32 + (l >> 4) * 8;
        unsigned short o[8];
        #pragma unroll
        for (int e = 0; e < 8; ++e) {
            int k = kbase + e;
            float w = (k < IC) ? Wl0[k * HC + n] : Wr0[(k - IC) * HC + n];
            o[e] = f2bf(w);
        }
        #pragma unroll
        for (int e = 0; e < 8; ++e) Bp[(size_t)tt * 8 + e] = o[e];
    } else if (b < TOBF16_BLOCKS + WPACK_BLOCKS + ZERO_BLOCKS) {
        int idx = (b - TOBF16_BLOCKS - WPACK_BLOCKS) * 256 + t;
        if (idx <= NN) degi[idx] = 0;         // degi[NN] is the ticket counter
    } else {
        int idx = (b - TOBF16_BLOCKS - WPACK_BLOCKS - ZERO_BLOCKS) * 256 + t;
        if (idx < 75008) gr[idx] = make_float4(0.f, 0.f, 0.f, 0.f);  // g and r (contiguous)
    }
}

// ---------------- CSR build: single atomic pass emits degree AND rank ----------------
__global__ __launch_bounds__(256) void k_deg(const int* __restrict__ ei,
                                             int* __restrict__ degi,
                                             int* __restrict__ pos) {
    int e = blockIdx.x * blockDim.x + threadIdx.x;
    if (e >= NE) return;
    pos[e] = atomicAdd(&degi[ei[NE + e]], 1);
}

// ticket allocator: disjoint contiguous regions; order never needed downstream.
__global__ __launch_bounds__(256) void k_ticket(const int* __restrict__ degi,
                                                int* __restrict__ counter,
                                                int* __restrict__ rowstart) {
    int n = blockIdx.x * blockDim.x + threadIdx.x;
    if (n >= NN) return;
    rowstart[n] = atomicAdd(counter, degi[n]);
}

// plain-store fill using precomputed rank
__global__ __launch_bounds__(256) void k_fill(const int* __restrict__ ei,
                                              const int* __restrict__ rowstart,
                                              const int* __restrict__ pos,
                                              int* __restrict__ csr) {
    int e = blockIdx.x * blockDim.x + threadIdx.x;
    if (e >= NE) return;
    int src = ei[e];
    int dst = ei[NE + e];
    csr[rowstart[dst] + pos[e]] = src;
}

// ---------------- gather-mean: 4 edge-subgroups x 16 lanes x uint4 ----------------
__global__ __launch_bounds__(256) void k_agg(const int* __restrict__ rowstart,
                                             const int* __restrict__ degi,
                                             const int* __restrict__ csr,
                                             unsigned short* __restrict__ Ab) {
    int wid = (blockIdx.x * blockDim.x + threadIdx.x) >> 6;
    int lane = threadIdx.x & 63;
    if (wid >= NN) return;
    int deg = degi[wid];
    int beg = rowstart[wid];
    int sg = lane >> 4;
    int s  = lane & 15;
    const uint4* base = (const uint4*)Ab;     // 32 uint4 per 512B row

    float a[8] = {0.f, 0.f, 0.f, 0.f, 0.f, 0.f, 0.f, 0.f};
    for (int j = beg + sg; j < beg + deg; j += 4) {
        int src = csr[j];
        uint4 v = base[(size_t)src * 32 + 16 + s];
        a[0] += bflo(v.x); a[1] += bfhi(v.x);
        a[2] += bflo(v.y); a[3] += bfhi(v.y);
        a[4] += bflo(v.z); a[5] += bfhi(v.z);
        a[6] += bflo(v.w); a[7] += bfhi(v.w);
    }
    #pragma unroll
    for (int m = 16; m <= 32; m <<= 1)
        #pragma unroll
        for (int i = 0; i < 8; ++i) a[i] += __shfl_xor(a[i], m);

    if (sg == 0) {
        float inv = 1.0f / fmaxf((float)deg, 1.0f);
        uint4 o;
        o.x = ((unsigned int)f2bf(a[1] * inv) << 16) | f2bf(a[0] * inv);
        o.y = ((unsigned int)f2bf(a[3] * inv) << 16) | f2bf(a[2] * inv);
        o.z = ((unsigned int)f2bf(a[5] * inv) << 16) | f2bf(a[4] * inv);
        o.w = ((unsigned int)f2bf(a[7] * inv) << 16) | f2bf(a[6] * inv);
        ((uint4*)Ab)[(size_t)wid * 32 + s] = o;
    }
}

// ---------------- MFMA GEMM v2: col-half split, full B-half resident in LDS ----------------
// grid (NNP/256, 2); 512 thr = 8 waves; block handles 256 nodes x 128 cols (half h).
// H = relu(Ab @ [Wl0;Wr0] + bl0) on this col-half; partial g/r accumulated by
// exactly-2-way atomicAdd onto zeroed buffers (commutative -> deterministic).
#define EPILOGUE(ACC, ROWOFF)                                                     \
    do {                                                                          \
        float pl[4][3] = {{0.f}}, pr[4][3] = {{0.f}};                             \
        _Pragma("unroll") for (int nt = 0; nt < 8; ++nt) {                        \
            int c = nt * 16 + (l & 15);                                           \
            float bcol = bls[c];                                                  \
            _Pragma("unroll") for (int e = 0; e < 4; ++e) {                       \
                float hv = fmaxf(ACC[nt][e] + bcol, 0.0f);                        \
                _Pragma("unroll") for (int j = 0; j < 3; ++j) {                   \
                    pl[e][j] = fmaf(hv, wl1s[c][j], pl[e][j]);                    \
                    pr[e][j] = fmaf(hv, wr1s[c][j], pr[e][j]);                    \
                }                                                                 \
            }                                                                     \
        }                                                                         \
        _Pragma("unroll") for (int m = 1; m <= 8; m <<= 1)                        \
            _Pragma("unroll") for (int e = 0; e < 4; ++e)                         \
                _Pragma("unroll") for (int j = 0; j < 3; ++j) {                   \
                    pl[e][j] += __shfl_xor(pl[e][j], m);                          \
                    pr[e][j] += __shfl_xor(pr[e][j], m);                          \
                }                                                                 \
        if ((l & 15) == 0) {                                                      \
            _Pragma("unroll") for (int e = 0; e < 4; ++e) {                       \
                int node = r0 + (ROWOFF) + (l >> 4) * 4 + e;                      \
                if (node < NN) {                                                  \
                    _Pragma("unroll") for (int j = 0; j < 3; ++j) {               \
                        unsafeAtomicAdd(&g[node * 3 + j], pl[e][j]);              \
                        unsafeAtomicAdd(&r[node * 3 + j], pr[e][j]);              \
                    }                                                             \
                }                                                                 \
            }                                                                     \
        }                                                                         \
    } while (0)

__global__ __launch_bounds__(512) void k_gemm(const unsigned short* __restrict__ Ab,
                                              const unsigned short* __restrict__ Bp,
                                              const float* __restrict__ bl0,
                                              const float* __restrict__ Wl1,
                                              const float* __restrict__ Wr1,
                                              float* __restrict__ g,
                                              float* __restrict__ r) {
    __shared__ float4 Bs[4096];              // 64 KB: this col-half of packed B, all K
    __shared__ float wl1s[128][3];
    __shared__ float wr1s[128][3];
    __shared__ float bls[128];

    int t = threadIdx.x;
    int h = blockIdx.y;                      // col half: cols h*128 .. h*128+127
    int nbase = blockIdx.x * 256;

    // stage B half: LDS float4 q -> (kt=q>>9, ntl=(q>>6)&7, l=q&63); src nt = h*8+ntl
    const float4* Bp4 = (const float4*)Bp;
    #pragma unroll
    for (int i = 0; i < 8; ++i) {
        int q = i * 512 + t;
        int kt = q >> 9, ntl = (q >> 6) & 7, lq = q & 63;
        Bs[q] = Bp4[(kt * 16 + h * 8 + ntl) * 64 + lq];
    }
    for (int i = t; i < 128 * 3; i += 512) {
        int c = i / 3, j = i % 3;
        int col = h * 128 + c;
        wl1s[c][j] = Wl1[col * 3 + j];
        wr1s[c][j] = Wr1[col * 3 + j];
    }
    if (t < 128) bls[t] = bl0[h * 128 + t];
    __syncthreads();

    int w = t >> 6, l = t & 63;
    int r0 = nbase + w * 32;                 // wave's rows: two 16-row tiles
    const short8* A8a = (const short8*)Ab + ((size_t)(r0 + (l & 15)) * 32 + (l >> 4));
    const short8* A8b = A8a + 16 * 32;       // +16 rows

    f32x4 acc0[8], acc1[8];
    #pragma unroll
    for (int i = 0; i < 8; ++i) { acc0[i] = (f32x4){0.f,0.f,0.f,0.f}; acc1[i] = (f32x4){0.f,0.f,0.f,0.f}; }

    const short8* B8 = (const short8*)Bs + l;
    #pragma unroll
    for (int kt = 0; kt < 8; ++kt) {
        short8 af0 = A8a[kt * 4];
        short8 af1 = A8b[kt * 4];
        #pragma unroll
        for (int nt = 0; nt < 8; ++nt) {
            short8 bf = B8[(kt * 8 + nt) * 64];
            acc0[nt] = __builtin_amdgcn_mfma_f32_16x16x32_bf16(af0, bf, acc0[nt], 0, 0, 0);
            acc1[nt] = __builtin_amdgcn_mfma_f32_16x16x32_bf16(af1, bf, acc1[nt], 0, 0, 0);
        }
    }

    EPILOGUE(acc0, 0);
    EPILOGUE(acc1, 16);
}

// ---------------- fused layer-1 aggregation by GATHER + final output ----------------
__global__ __launch_bounds__(256) void k_out(const int* __restrict__ rowstart,
                                             const int* __restrict__ degi,
                                             const int* __restrict__ csr,
                                             const float* __restrict__ g,
                                             const float* __restrict__ r,
                                             const float* __restrict__ bl1,
                                             float* __restrict__ out) {
    int tid = blockIdx.x * 256 + threadIdx.x;
    int n = tid >> 3;
    int sl = tid & 7;
    if (n >= NN) return;
    int deg = degi[n];
    int beg = rowstart[n];
    float s0 = 0.f, s1 = 0.f, s2 = 0.f;
    for (int j = beg + sl; j < beg + deg; j += 8) {
        int src = csr[j];
        s0 += g[src * 3 + 0];
        s1 += g[src * 3 + 1];
        s2 += g[src * 3 + 2];
    }
    #pragma unroll
    for (int m = 1; m < 8; m <<= 1) {
        s0 += __shfl_xor(s0, m);
        s1 += __shfl_xor(s1, m);
        s2 += __shfl_xor(s2, m);
    }
    if (sl == 0) {
        float inv = 1.0f / fmaxf((float)deg, 1.0f);
        out[n * 3 + 0] = s0 * inv + bl1[0] + r[n * 3 + 0];
        out[n * 3 + 1] = s1 * inv + bl1[1] + r[n * 3 + 1];
        out[n * 3 + 2] = s2 * inv + bl1[2] + r[n * 3 + 2];
    }
}

extern "C" void kernel_launch(void* const* d_in, const int* in_sizes, int n_in,
                              void* d_out, int out_size, void* d_ws, size_t ws_size,
                              hipStream_t stream) {
    const float* x   = (const float*)d_in[0];
    const int*   ei  = (const int*)d_in[1];
    const float* Wl0 = (const float*)d_in[2];
    const float* bl0 = (const float*)d_in[3];
    const float* Wr0 = (const float*)d_in[4];
    const float* Wl1 = (const float*)d_in[5];
    const float* bl1 = (const float*)d_in[6];
    const float* Wr1 = (const float*)d_in[7];
    float* out = (float*)d_out;

    char* ws = (char*)d_ws;
    int*            degi     = (int*)(ws);                        //    200,064 (NN + counter + pad)
    int*            rowstart = (int*)(ws + 200064);               //    200,064
    int*            pos      = (int*)(ws + 400128);               //  2,560,000
    int*            csr      = (int*)(ws + 2960128);              //  2,560,000
    unsigned short* Ab       = (unsigned short*)(ws + 5520128);   // 25,690,112 (NNP*256*2)
    unsigned short* Bp       = (unsigned short*)(ws + 31210240);  //    131,072
    float*          g        = (float*)(ws + 31341312);           //    600,064
    float*          r        = (float*)(ws + 31941376);           //    600,064  -> ~32.5 MB

    int* counter = degi + NN;

    k_prep  <<<TOBF16_BLOCKS + WPACK_BLOCKS + ZERO_BLOCKS + GR0_BLOCKS, 256, 0, stream>>>
            (x, Wl0, Wr0, Ab, Bp, degi, (float4*)g);
    k_deg   <<<(NE + 255) / 256, 256, 0, stream>>>(ei, degi, pos);
    k_ticket<<<(NN + 255) / 256, 256, 0, stream>>>(degi, counter, rowstart);
    k_fill  <<<(NE + 255) / 256, 256, 0, stream>>>(ei, rowstart, pos, csr);
    k_agg   <<<(NN * 64 + 255) / 256, 256, 0, stream>>>(rowstart, degi, csr, Ab);
    k_gemm  <<<dim3(NNP / 256, 2), 512, 0, stream>>>(Ab, Bp, bl0, Wl1, Wr1, g, r);
    k_out   <<<(NN * 8 + 255) / 256, 256, 0, stream>>>(rowstart, degi, csr, g, r, bl1, out);
}

// Round 10
// 125.019 us; speedup vs baseline: 1.1006x; 1.1006x over previous
//
#include <hip/hip_runtime.h>

#define NN 50000
#define NNP 50048   // Ab rows padded to multiple of 64
#define NE 640000
#define IC 128
#define HC 256
#define OC 3

#define TOBF16_BLOCKS (NN * IC / 4 / 256)          // 6250
#define WPACK_BLOCKS  32
#define ZERO_BLOCKS   ((NN + 1 + 255) / 256)       // 196 (degi[0..NN-1] + counter at degi[NN])

typedef __attribute__((ext_vector_type(8))) short short8;
typedef __attribute__((ext_vector_type(4))) float f32x4;

__device__ __forceinline__ unsigned short f2bf(float f) {   // fp32 -> bf16 RNE
    unsigned int u = __float_as_uint(f);
    unsigned int r = u + 0x7FFFu + ((u >> 16) & 1u);
    return (unsigned short)(r >> 16);
}
__device__ __forceinline__ float bflo(unsigned int v) { return __uint_as_float(v << 16); }
__device__ __forceinline__ float bfhi(unsigned int v) { return __uint_as_float(v & 0xffff0000u); }

// ---------------- prep: zero degi+counter | x->bf16 | pack W ----------------
__global__ __launch_bounds__(256) void k_prep(const float* __restrict__ x,
                                              const float* __restrict__ Wl0,
                                              const float* __restrict__ Wr0,
                                              unsigned short* __restrict__ Ab,
                                              unsigned short* __restrict__ Bp,
                                              int* __restrict__ degi) {
    int b = blockIdx.x;
    int t = threadIdx.x;
    if (b < TOBF16_BLOCKS) {
        // x -> bf16 into right half of Ab (Ab: ushort[NNP][256], cols 128..255 = x)
        int i = b * 256 + t;                  // over NN*IC/4 float4s
        int n = i >> 5;
        int c = (i & 31) * 4;
        float4 v = ((const float4*)x)[i];
        ushort4 o;
        o.x = f2bf(v.x); o.y = f2bf(v.y); o.z = f2bf(v.z); o.w = f2bf(v.w);
        *(ushort4*)&Ab[(size_t)n * 256 + 128 + c] = o;
    } else if (b < TOBF16_BLOCKS + WPACK_BLOCKS) {
        // pack [Wl0;Wr0] into MFMA B-fragment order:
        // Bp[kt(8)][nt(16)][lane(64)][e(8)], B[k][n]: k=kt*32+(lane>>4)*8+e, n=nt*16+(lane&15)
        int tt = (b - TOBF16_BLOCKS) * 256 + t;     // 8192 threads
        int l = tt & 63;
        int nt = (tt >> 6) & 15;
        int kt = tt >> 10;
        int n = nt * 16 + (l & 15);
        int kbase = kt * 32 + (l >> 4) * 8;
        unsigned short o[8];
        #pragma unroll
        for (int e = 0; e < 8; ++e) {
            int k = kbase + e;
            float w = (k < IC) ? Wl0[k * HC + n] : Wr0[(k - IC) * HC + n];
            o[e] = f2bf(w);
        }
        #pragma unroll
        for (int e = 0; e < 8; ++e) Bp[(size_t)tt * 8 + e] = o[e];
    } else {
        int idx = (b - TOBF16_BLOCKS - WPACK_BLOCKS) * 256 + t;
        if (idx <= NN) degi[idx] = 0;         // degi[NN] is the ticket counter
    }
}

// ---------------- CSR build: single atomic pass emits degree AND rank ----------------
__global__ __launch_bounds__(256) void k_deg(const int* __restrict__ ei,
                                             int* __restrict__ degi,
                                             int* __restrict__ pos) {
    int e = blockIdx.x * blockDim.x + threadIdx.x;
    if (e >= NE) return;
    pos[e] = atomicAdd(&degi[ei[NE + e]], 1);
}

// ticket allocator: disjoint contiguous regions; order never needed downstream.
__global__ __launch_bounds__(256) void k_ticket(const int* __restrict__ degi,
                                                int* __restrict__ counter,
                                                int* __restrict__ rowstart) {
    int n = blockIdx.x * blockDim.x + threadIdx.x;
    if (n >= NN) return;
    rowstart[n] = atomicAdd(counter, degi[n]);
}

// plain-store fill using precomputed rank
__global__ __launch_bounds__(256) void k_fill(const int* __restrict__ ei,
                                              const int* __restrict__ rowstart,
                                              const int* __restrict__ pos,
                                              int* __restrict__ csr) {
    int e = blockIdx.x * blockDim.x + threadIdx.x;
    if (e >= NE) return;
    int src = ei[e];
    int dst = ei[NE + e];
    csr[rowstart[dst] + pos[e]] = src;
}

// ---------------- gather-mean: 8 edge-subgroups x 8 lanes x 2 uint4 (32B/lane) ----------------
__global__ __launch_bounds__(256) void k_agg(const int* __restrict__ rowstart,
                                             const int* __restrict__ degi,
                                             const int* __restrict__ csr,
                                             unsigned short* __restrict__ Ab) {
    int wid = (blockIdx.x * blockDim.x + threadIdx.x) >> 6;
    int lane = threadIdx.x & 63;
    if (wid >= NN) return;
    int deg = degi[wid];
    int beg = rowstart[wid];
    int sg = lane >> 3;        // edge subgroup 0..7 (8 edges in flight per wave)
    int s  = lane & 7;         // this lane covers uint4 slots s and s+8 of the x-half
    const uint4* base = (const uint4*)Ab;     // 32 uint4 per 512B row

    float a[16];
    #pragma unroll
    for (int i = 0; i < 16; ++i) a[i] = 0.f;

    for (int j = beg + sg; j < beg + deg; j += 8) {
        int src = csr[j];
        uint4 v0 = base[(size_t)src * 32 + 16 + s];
        uint4 v1 = base[(size_t)src * 32 + 24 + s];
        a[0] += bflo(v0.x); a[1] += bfhi(v0.x);
        a[2] += bflo(v0.y); a[3] += bfhi(v0.y);
        a[4] += bflo(v0.z); a[5] += bfhi(v0.z);
        a[6] += bflo(v0.w); a[7] += bfhi(v0.w);
        a[8]  += bflo(v1.x); a[9]  += bfhi(v1.x);
        a[10] += bflo(v1.y); a[11] += bfhi(v1.y);
        a[12] += bflo(v1.z); a[13] += bfhi(v1.z);
        a[14] += bflo(v1.w); a[15] += bfhi(v1.w);
    }
    #pragma unroll
    for (int m = 8; m <= 32; m <<= 1)
        #pragma unroll
        for (int i = 0; i < 16; ++i) a[i] += __shfl_xor(a[i], m);

    if (sg == 0) {
        float inv = 1.0f / fmaxf((float)deg, 1.0f);
        uint4 o0, o1;
        o0.x = ((unsigned int)f2bf(a[1] * inv) << 16) | f2bf(a[0] * inv);
        o0.y = ((unsigned int)f2bf(a[3] * inv) << 16) | f2bf(a[2] * inv);
        o0.z = ((unsigned int)f2bf(a[5] * inv) << 16) | f2bf(a[4] * inv);
        o0.w = ((unsigned int)f2bf(a[7] * inv) << 16) | f2bf(a[6] * inv);
        o1.x = ((unsigned int)f2bf(a[9]  * inv) << 16) | f2bf(a[8]  * inv);
        o1.y = ((unsigned int)f2bf(a[11] * inv) << 16) | f2bf(a[10] * inv);
        o1.z = ((unsigned int)f2bf(a[13] * inv) << 16) | f2bf(a[12] * inv);
        o1.w = ((unsigned int)f2bf(a[15] * inv) << 16) | f2bf(a[14] * inv);
        ((uint4*)Ab)[(size_t)wid * 32 + s] = o0;
        ((uint4*)Ab)[(size_t)wid * 32 + 8 + s] = o1;
    }
}

// ---------------- MFMA GEMM + fused epilogue (R8 structure + A-frag prefetch) ----------------
// H = relu(Ab @ [Wl0;Wr0] + bl0); g = H@Wl1; r = H@Wr1
__global__ __launch_bounds__(256) void k_gemm(const unsigned short* __restrict__ Ab,
                                              const unsigned short* __restrict__ Bp,
                                              const float* __restrict__ bl0,
                                              const float* __restrict__ Wl1,
                                              const float* __restrict__ Wr1,
                                              float* __restrict__ g,
                                              float* __restrict__ r) {
    __shared__ float4 Bs[2048];          // 32 KB: one K-quarter of packed B
    __shared__ float wl1s[HC][3];
    __shared__ float wr1s[HC][3];
    __shared__ float bls[HC];

    int t = threadIdx.x;
    for (int i = t; i < HC * 3; i += 256) {
        wl1s[i / 3][i % 3] = Wl1[i];
        wr1s[i / 3][i % 3] = Wr1[i];
    }
    for (int i = t; i < HC; i += 256) bls[i] = bl0[i];

    int w = t >> 6, l = t & 63;
    int n0 = blockIdx.x * 64 + w * 16;

    f32x4 acc[16];
    #pragma unroll
    for (int i = 0; i < 16; ++i) acc[i] = (f32x4){0.f, 0.f, 0.f, 0.f};

    // A-frag: lane l supplies A[n0 + (l&15)][kt*32 + (l>>4)*8 + e]
    // prefetch ALL 8 K-step fragments upfront: the L3 latency hides under the
    // first B-staging + barrier instead of stalling each quarter phase.
    const short8* A8 = (const short8*)Ab + ((size_t)(n0 + (l & 15)) * 32 + (l >> 4));
    short8 afr[8];
    #pragma unroll
    for (int kt = 0; kt < 8; ++kt) afr[kt] = A8[kt * 4];

    for (int q = 0; q < 4; ++q) {
        __syncthreads();
        const float4* gsrc = (const float4*)(Bp + (size_t)q * 16384);  // 32KB quarter
        #pragma unroll
        for (int i = 0; i < 8; ++i)
            Bs[i * 256 + t] = gsrc[i * 256 + t];
        __syncthreads();
        #pragma unroll
        for (int j = 0; j < 2; ++j) {
            int kt = q * 2 + j;
            const short8* B8 = (const short8*)Bs + (j * 1024 + l);
            #pragma unroll
            for (int nt = 0; nt < 16; ++nt) {
                short8 bf = B8[nt * 64];
                acc[nt] = __builtin_amdgcn_mfma_f32_16x16x32_bf16(afr[kt], bf, acc[nt], 0, 0, 0);
            }
        }
    }

    // epilogue: D lane l reg e = H[row=(l>>4)*4+e][col=nt*16+(l&15)]
    float pl[4][3] = {{0.f}}, pr[4][3] = {{0.f}};
    #pragma unroll
    for (int nt = 0; nt < 16; ++nt) {
        int col = nt * 16 + (l & 15);
        float b = bls[col];
        #pragma unroll
        for (int e = 0; e < 4; ++e) {
            float h = fmaxf(acc[nt][e] + b, 0.0f);
            #pragma unroll
            for (int j = 0; j < 3; ++j) {
                pl[e][j] = fmaf(h, wl1s[col][j], pl[e][j]);
                pr[e][j] = fmaf(h, wr1s[col][j], pr[e][j]);
            }
        }
    }
    #pragma unroll
    for (int m = 1; m <= 8; m <<= 1) {
        #pragma unroll
        for (int e = 0; e < 4; ++e)
            #pragma unroll
            for (int j = 0; j < 3; ++j) {
                pl[e][j] += __shfl_xor(pl[e][j], m);
                pr[e][j] += __shfl_xor(pr[e][j], m);
            }
    }
    if ((l & 15) == 0) {
        #pragma unroll
        for (int e = 0; e < 4; ++e) {
            int node = n0 + (l >> 4) * 4 + e;
            if (node < NN) {
                #pragma unroll
                for (int j = 0; j < 3; ++j) {
                    g[node * 3 + j] = pl[e][j];
                    r[node * 3 + j] = pr[e][j];
                }
            }
        }
    }
}

// ---------------- fused layer-1 aggregation by GATHER + final output ----------------
__global__ __launch_bounds__(256) void k_out(const int* __restrict__ rowstart,
                                             const int* __restrict__ degi,
                                             const int* __restrict__ csr,
                                             const float* __restrict__ g,
                                             const float* __restrict__ r,
                                             const float* __restrict__ bl1,
                                             float* __restrict__ out) {
    int tid = blockIdx.x * 256 + threadIdx.x;
    int n = tid >> 3;
    int sl = tid & 7;
    if (n >= NN) return;
    int deg = degi[n];
    int beg = rowstart[n];
    float s0 = 0.f, s1 = 0.f, s2 = 0.f;
    for (int j = beg + sl; j < beg + deg; j += 8) {
        int src = csr[j];
        s0 += g[src * 3 + 0];
        s1 += g[src * 3 + 1];
        s2 += g[src * 3 + 2];
    }
    #pragma unroll
    for (int m = 1; m < 8; m <<= 1) {
        s0 += __shfl_xor(s0, m);
        s1 += __shfl_xor(s1, m);
        s2 += __shfl_xor(s2, m);
    }
    if (sl == 0) {
        float inv = 1.0f / fmaxf((float)deg, 1.0f);
        out[n * 3 + 0] = s0 * inv + bl1[0] + r[n * 3 + 0];
        out[n * 3 + 1] = s1 * inv + bl1[1] + r[n * 3 + 1];
        out[n * 3 + 2] = s2 * inv + bl1[2] + r[n * 3 + 2];
    }
}

extern "C" void kernel_launch(void* const* d_in, const int* in_sizes, int n_in,
                              void* d_out, int out_size, void* d_ws, size_t ws_size,
                              hipStream_t stream) {
    const float* x   = (const float*)d_in[0];
    const int*   ei  = (const int*)d_in[1];
    const float* Wl0 = (const float*)d_in[2];
    const float* bl0 = (const float*)d_in[3];
    const float* Wr0 = (const float*)d_in[4];
    const float* Wl1 = (const float*)d_in[5];
    const float* bl1 = (const float*)d_in[6];
    const float* Wr1 = (const float*)d_in[7];
    float* out = (float*)d_out;

    char* ws = (char*)d_ws;
    int*            degi     = (int*)(ws);                        //    200,064 (NN + counter + pad)
    int*            rowstart = (int*)(ws + 200064);               //    200,064
    int*            pos      = (int*)(ws + 400128);               //  2,560,000
    int*            csr      = (int*)(ws + 2960128);              //  2,560,000
    unsigned short* Ab       = (unsigned short*)(ws + 5520128);   // 25,624,576 (NNP*256*2)
    unsigned short* Bp       = (unsigned short*)(ws + 31144704);  //    131,072
    float*          g        = (float*)(ws + 31275776);           //    600,064
    float*          r        = (float*)(ws + 31875840);           //    600,064  -> ~32.5 MB

    int* counter = degi + NN;

    k_prep  <<<TOBF16_BLOCKS + WPACK_BLOCKS + ZERO_BLOCKS, 256, 0, stream>>>(x, Wl0, Wr0, Ab, Bp, degi);
    k_deg   <<<(NE + 255) / 256, 256, 0, stream>>>(ei, degi, pos);
    k_ticket<<<(NN + 255) / 256, 256, 0, stream>>>(degi, counter, rowstart);
    k_fill  <<<(NE + 255) / 256, 256, 0, stream>>>(ei, rowstart, pos, csr);
    k_agg   <<<(NN * 64 + 255) / 256, 256, 0, stream>>>(rowstart, degi, csr, Ab);
    k_gemm  <<<(NN + 63) / 64, 256, 0, stream>>>(Ab, Bp, bl0, Wl1, Wr1, g, r);
    k_out   <<<(NN * 8 + 255) / 256, 256, 0, stream>>>(rowstart, degi, csr, g, r, bl1, out);
}

// Round 11
// 109.050 us; speedup vs baseline: 1.2617x; 1.1464x over previous
//
#include <hip/hip_runtime.h>

#define NN 50000
#define NNP 50048   // Ab rows padded to multiple of 64
#define NE 640000
#define IC 128
#define HC 256
#define OC 3
#define PAD 64      // padded CSR row capacity; P(deg>=64)~1e-25 for Poisson(12.8); guarded anyway

#define TOBF16_BLOCKS (NN * IC / 4 / 256)          // 6250
#define WPACK_BLOCKS  32
#define ZERO_BLOCKS   ((NN + 255) / 256)           // 196

typedef __attribute__((ext_vector_type(8))) short short8;
typedef __attribute__((ext_vector_type(4))) float f32x4;

__device__ __forceinline__ unsigned short f2bf(float f) {   // fp32 -> bf16 RNE
    unsigned int u = __float_as_uint(f);
    unsigned int r = u + 0x7FFFu + ((u >> 16) & 1u);
    return (unsigned short)(r >> 16);
}
__device__ __forceinline__ float bflo(unsigned int v) { return __uint_as_float(v << 16); }
__device__ __forceinline__ float bfhi(unsigned int v) { return __uint_as_float(v & 0xffff0000u); }

// ---------------- prep: zero degi | x->bf16 | pack W ----------------
__global__ __launch_bounds__(256) void k_prep(const float* __restrict__ x,
                                              const float* __restrict__ Wl0,
                                              const float* __restrict__ Wr0,
                                              unsigned short* __restrict__ Ab,
                                              unsigned short* __restrict__ Bp,
                                              int* __restrict__ degi) {
    int b = blockIdx.x;
    int t = threadIdx.x;
    if (b < TOBF16_BLOCKS) {
        // x -> bf16 into right half of Ab (Ab: ushort[NNP][256], cols 128..255 = x)
        int i = b * 256 + t;                  // over NN*IC/4 float4s
        int n = i >> 5;
        int c = (i & 31) * 4;
        float4 v = ((const float4*)x)[i];
        ushort4 o;
        o.x = f2bf(v.x); o.y = f2bf(v.y); o.z = f2bf(v.z); o.w = f2bf(v.w);
        *(ushort4*)&Ab[(size_t)n * 256 + 128 + c] = o;
    } else if (b < TOBF16_BLOCKS + WPACK_BLOCKS) {
        // pack [Wl0;Wr0] into MFMA B-fragment order:
        // Bp[kt(8)][nt(16)][lane(64)][e(8)], B[k][n]: k=kt*32+(lane>>4)*8+e, n=nt*16+(lane&15)
        int tt = (b - TOBF16_BLOCKS) * 256 + t;     // 8192 threads
        int l = tt & 63;
        int nt = (tt >> 6) & 15;
        int kt = tt >> 10;
        int n = nt * 16 + (l & 15);
        int kbase = kt * 32 + (l >> 4) * 8;
        unsigned short o[8];
        #pragma unroll
        for (int e = 0; e < 8; ++e) {
            int k = kbase + e;
            float w = (k < IC) ? Wl0[k * HC + n] : Wr0[(k - IC) * HC + n];
            o[e] = f2bf(w);
        }
        #pragma unroll
        for (int e = 0; e < 8; ++e) Bp[(size_t)tt * 8 + e] = o[e];
    } else {
        int idx = (b - TOBF16_BLOCKS - WPACK_BLOCKS) * 256 + t;
        if (idx < NN) degi[idx] = 0;
    }
}

// ---------------- one-pass padded-CSR build: degree + slot in a single atomic ----------------
__global__ __launch_bounds__(256) void k_build(const int* __restrict__ ei,
                                               int* __restrict__ degi,
                                               int* __restrict__ csrp) {
    int e = blockIdx.x * blockDim.x + threadIdx.x;
    if (e >= NE) return;
    int src = ei[e];
    int dst = ei[NE + e];
    int rank = atomicAdd(&degi[dst], 1);
    if (rank < PAD) csrp[dst * PAD + rank] = src;
}

// ---------------- gather-mean: 8 edge-subgroups x 8 lanes x 2 uint4 (32B/lane) ----------------
__global__ __launch_bounds__(256) void k_agg(const int* __restrict__ degi,
                                             const int* __restrict__ csrp,
                                             unsigned short* __restrict__ Ab) {
    int wid = (blockIdx.x * blockDim.x + threadIdx.x) >> 6;
    int lane = threadIdx.x & 63;
    if (wid >= NN) return;
    int deg = min(degi[wid], PAD);
    int beg = wid * PAD;
    int sg = lane >> 3;        // edge subgroup 0..7 (8 edges in flight per wave)
    int s  = lane & 7;         // this lane covers uint4 slots s and s+8 of the x-half
    const uint4* base = (const uint4*)Ab;     // 32 uint4 per 512B row

    float a[16];
    #pragma unroll
    for (int i = 0; i < 16; ++i) a[i] = 0.f;

    for (int j = sg; j < deg; j += 8) {
        int src = csrp[beg + j];
        uint4 v0 = base[(size_t)src * 32 + 16 + s];
        uint4 v1 = base[(size_t)src * 32 + 24 + s];
        a[0] += bflo(v0.x); a[1] += bfhi(v0.x);
        a[2] += bflo(v0.y); a[3] += bfhi(v0.y);
        a[4] += bflo(v0.z); a[5] += bfhi(v0.z);
        a[6] += bflo(v0.w); a[7] += bfhi(v0.w);
        a[8]  += bflo(v1.x); a[9]  += bfhi(v1.x);
        a[10] += bflo(v1.y); a[11] += bfhi(v1.y);
        a[12] += bflo(v1.z); a[13] += bfhi(v1.z);
        a[14] += bflo(v1.w); a[15] += bfhi(v1.w);
    }
    #pragma unroll
    for (int m = 8; m <= 32; m <<= 1)
        #pragma unroll
        for (int i = 0; i < 16; ++i) a[i] += __shfl_xor(a[i], m);

    if (sg == 0) {
        float inv = 1.0f / fmaxf((float)deg, 1.0f);
        uint4 o0, o1;
        o0.x = ((unsigned int)f2bf(a[1] * inv) << 16) | f2bf(a[0] * inv);
        o0.y = ((unsigned int)f2bf(a[3] * inv) << 16) | f2bf(a[2] * inv);
        o0.z = ((unsigned int)f2bf(a[5] * inv) << 16) | f2bf(a[4] * inv);
        o0.w = ((unsigned int)f2bf(a[7] * inv) << 16) | f2bf(a[6] * inv);
        o1.x = ((unsigned int)f2bf(a[9]  * inv) << 16) | f2bf(a[8]  * inv);
        o1.y = ((unsigned int)f2bf(a[11] * inv) << 16) | f2bf(a[10] * inv);
        o1.z = ((unsigned int)f2bf(a[13] * inv) << 16) | f2bf(a[12] * inv);
        o1.w = ((unsigned int)f2bf(a[15] * inv) << 16) | f2bf(a[14] * inv);
        ((uint4*)Ab)[(size_t)wid * 32 + s] = o0;
        ((uint4*)Ab)[(size_t)wid * 32 + 8 + s] = o1;
    }
}

// ---------------- MFMA GEMM + fused epilogue ----------------
// H = relu(Ab @ [Wl0;Wr0] + bl0); g = H@Wl1; r = H@Wr1
__global__ __launch_bounds__(256) void k_gemm(const unsigned short* __restrict__ Ab,
                                              const unsigned short* __restrict__ Bp,
                                              const float* __restrict__ bl0,
                                              const float* __restrict__ Wl1,
                                              const float* __restrict__ Wr1,
                                              float* __restrict__ g,
                                              float* __restrict__ r) {
    __shared__ float4 Bs[2048];          // 32 KB: one K-quarter of packed B
    __shared__ float wl1s[HC][3];
    __shared__ float wr1s[HC][3];
    __shared__ float bls[HC];

    int t = threadIdx.x;
    for (int i = t; i < HC * 3; i += 256) {
        wl1s[i / 3][i % 3] = Wl1[i];
        wr1s[i / 3][i % 3] = Wr1[i];
    }
    for (int i = t; i < HC; i += 256) bls[i] = bl0[i];

    int w = t >> 6, l = t & 63;
    int n0 = blockIdx.x * 64 + w * 16;

    f32x4 acc[16];
    #pragma unroll
    for (int i = 0; i < 16; ++i) acc[i] = (f32x4){0.f, 0.f, 0.f, 0.f};

    // A-frag: lane l supplies A[n0 + (l&15)][kt*32 + (l>>4)*8 + e]; prefetch all 8 upfront
    const short8* A8 = (const short8*)Ab + ((size_t)(n0 + (l & 15)) * 32 + (l >> 4));
    short8 afr[8];
    #pragma unroll
    for (int kt = 0; kt < 8; ++kt) afr[kt] = A8[kt * 4];

    for (int q = 0; q < 4; ++q) {
        __syncthreads();
        const float4* gsrc = (const float4*)(Bp + (size_t)q * 16384);  // 32KB quarter
        #pragma unroll
        for (int i = 0; i < 8; ++i)
            Bs[i * 256 + t] = gsrc[i * 256 + t];
        __syncthreads();
        #pragma unroll
        for (int j = 0; j < 2; ++j) {
            int kt = q * 2 + j;
            const short8* B8 = (const short8*)Bs + (j * 1024 + l);
            #pragma unroll
            for (int nt = 0; nt < 16; ++nt) {
                short8 bf = B8[nt * 64];
                acc[nt] = __builtin_amdgcn_mfma_f32_16x16x32_bf16(afr[kt], bf, acc[nt], 0, 0, 0);
            }
        }
    }

    // epilogue: D lane l reg e = H[row=(l>>4)*4+e][col=nt*16+(l&15)]
    float pl[4][3] = {{0.f}}, pr[4][3] = {{0.f}};
    #pragma unroll
    for (int nt = 0; nt < 16; ++nt) {
        int col = nt * 16 + (l & 15);
        float b = bls[col];
        #pragma unroll
        for (int e = 0; e < 4; ++e) {
            float h = fmaxf(acc[nt][e] + b, 0.0f);
            #pragma unroll
            for (int j = 0; j < 3; ++j) {
                pl[e][j] = fmaf(h, wl1s[col][j], pl[e][j]);
                pr[e][j] = fmaf(h, wr1s[col][j], pr[e][j]);
            }
        }
    }
    #pragma unroll
    for (int m = 1; m <= 8; m <<= 1) {
        #pragma unroll
        for (int e = 0; e < 4; ++e)
            #pragma unroll
            for (int j = 0; j < 3; ++j) {
                pl[e][j] += __shfl_xor(pl[e][j], m);
                pr[e][j] += __shfl_xor(pr[e][j], m);
            }
    }
    if ((l & 15) == 0) {
        #pragma unroll
        for (int e = 0; e < 4; ++e) {
            int node = n0 + (l >> 4) * 4 + e;
            if (node < NN) {
                #pragma unroll
                for (int j = 0; j < 3; ++j) {
                    g[node * 3 + j] = pl[e][j];
                    r[node * 3 + j] = pr[e][j];
                }
            }
        }
    }
}

// ---------------- fused layer-1 aggregation by GATHER + final output ----------------
__global__ __launch_bounds__(256) void k_out(const int* __restrict__ degi,
                                             const int* __restrict__ csrp,
                                             const float* __restrict__ g,
                                             const float* __restrict__ r,
                                             const float* __restrict__ bl1,
                                             float* __restrict__ out) {
    int tid = blockIdx.x * 256 + threadIdx.x;
    int n = tid >> 3;
    int sl = tid & 7;
    if (n >= NN) return;
    int deg = min(degi[n], PAD);
    int beg = n * PAD;
    float s0 = 0.f, s1 = 0.f, s2 = 0.f;
    for (int j = sl; j < deg; j += 8) {
        int src = csrp[beg + j];
        s0 += g[src * 3 + 0];
        s1 += g[src * 3 + 1];
        s2 += g[src * 3 + 2];
    }
    #pragma unroll
    for (int m = 1; m < 8; m <<= 1) {
        s0 += __shfl_xor(s0, m);
        s1 += __shfl_xor(s1, m);
        s2 += __shfl_xor(s2, m);
    }
    if (sl == 0) {
        float inv = 1.0f / fmaxf((float)deg, 1.0f);
        out[n * 3 + 0] = s0 * inv + bl1[0] + r[n * 3 + 0];
        out[n * 3 + 1] = s1 * inv + bl1[1] + r[n * 3 + 1];
        out[n * 3 + 2] = s2 * inv + bl1[2] + r[n * 3 + 2];
    }
}

extern "C" void kernel_launch(void* const* d_in, const int* in_sizes, int n_in,
                              void* d_out, int out_size, void* d_ws, size_t ws_size,
                              hipStream_t stream) {
    const float* x   = (const float*)d_in[0];
    const int*   ei  = (const int*)d_in[1];
    const float* Wl0 = (const float*)d_in[2];
    const float* bl0 = (const float*)d_in[3];
    const float* Wr0 = (const float*)d_in[4];
    const float* Wl1 = (const float*)d_in[5];
    const float* bl1 = (const float*)d_in[6];
    const float* Wr1 = (const float*)d_in[7];
    float* out = (float*)d_out;

    char* ws = (char*)d_ws;
    int*            degi = (int*)(ws);                        //    200,064 (NN + pad)
    int*            csrp = (int*)(ws + 200064);               // 12,800,000 (NN*PAD*4)
    unsigned short* Ab   = (unsigned short*)(ws + 13000064);  // 25,624,576 (NNP*256*2)
    unsigned short* Bp   = (unsigned short*)(ws + 38624640);  //    131,072
    float*          g    = (float*)(ws + 38755712);           //    600,064
    float*          r    = (float*)(ws + 39355776);           //    600,064  -> ~40.0 MB

    k_prep <<<TOBF16_BLOCKS + WPACK_BLOCKS + ZERO_BLOCKS, 256, 0, stream>>>(x, Wl0, Wr0, Ab, Bp, degi);
    k_build<<<(NE + 255) / 256, 256, 0, stream>>>(ei, degi, csrp);
    k_agg  <<<(NN * 64 + 255) / 256, 256, 0, stream>>>(degi, csrp, Ab);
    k_gemm <<<(NN + 63) / 64, 256, 0, stream>>>(Ab, Bp, bl0, Wl1, Wr1, g, r);
    k_out  <<<(NN * 8 + 255) / 256, 256, 0, stream>>>(degi, csrp, g, r, bl1, out);
}